// Round 3
// baseline (168.424 us; speedup 1.0000x reference)
//
#include <hip/hip_runtime.h>
#include <stdint.h>

#define TILE 256

// Residue-type multiplicative bonuses (default 1.0)
__device__ __constant__ float BOND[20] = {
    1.05f, 1.30f, 1.10f, 1.20f, 1.00f, 1.10f, 1.20f, 1.00f, 1.40f, 1.00f,
    1.00f, 1.30f, 1.00f, 1.50f, 1.00f, 1.05f, 1.05f, 1.60f, 1.40f, 1.10f};

__global__ void k_init(int* __restrict__ counts, int* __restrict__ rankv,
                       int* __restrict__ maxn, int N) {
  int i = blockIdx.x * blockDim.x + threadIdx.x;
  if (i < N) { counts[i] = 0; rankv[i] = 0; }
  if (i == 0) *maxn = 0;
}

// Per-atom min distance to ligand; also stage positions with far-mask folded
// into x (non-far j -> 3e30 so d2 = inf, auto-excluded from neighbor counts).
__global__ void k_classify(const float* __restrict__ pos, const float* __restrict__ lig,
                           float* __restrict__ min_d, float4* __restrict__ posj,
                           int N, int M) {
#pragma clang fp contract(off)
  __shared__ float sl[3 * 256];
  int t = threadIdx.x;
  for (int idx = t; idx < M * 3; idx += blockDim.x) sl[idx] = lig[idx];
  __syncthreads();
  int i = blockIdx.x * blockDim.x + t;
  if (i >= N) return;
  float px = pos[3 * i], py = pos[3 * i + 1], pz = pos[3 * i + 2];
  float m = 3.4e38f;
  for (int j = 0; j < M; ++j) {
    float dx = px - sl[3 * j];
    float dy = py - sl[3 * j + 1];
    float dz = pz - sl[3 * j + 2];
    float d2 = dx * dx + dy * dy + dz * dz;
    m = fminf(m, d2);
  }
  float md = sqrtf(fmaxf(m, 1e-12f));
  min_d[i] = md;
  bool far = md > 8.0f;
  posj[i] = make_float4(far ? px : 3.0e30f, py, pz, 0.0f);
}

// N x N neighbor count among far atoms (0 < d2 < 25), LDS-tiled over j.
__global__ void k_count(const float* __restrict__ pos, const float4* __restrict__ posj,
                        int* __restrict__ counts, int N, int jChunk) {
#pragma clang fp contract(off)
  __shared__ float4 sj[TILE];
  int t = threadIdx.x;
  int i = blockIdx.x * TILE + t;
  bool valid = i < N;
  int ii = valid ? i : 0;
  float px = pos[3 * ii], py = pos[3 * ii + 1], pz = pos[3 * ii + 2];
  int j0 = blockIdx.y * jChunk;
  int j1 = j0 + jChunk;
  if (j1 > N) j1 = N;
  int cnt = 0;
  for (int jb = j0; jb < j1; jb += TILE) {
    __syncthreads();
    if (jb + t < N) sj[t] = posj[jb + t];
    else            sj[t] = make_float4(3.0e30f, 0.f, 0.f, 0.f);
    __syncthreads();
#pragma unroll 16
    for (int jj = 0; jj < TILE; ++jj) {
      float4 q = sj[jj];
      float dx = px - q.x;
      float dy = py - q.y;
      float dz = pz - q.z;
      float d2 = dx * dx + dy * dy + dz * dz;
      cnt += (d2 < 25.0f && d2 > 0.0f) ? 1 : 0;
    }
  }
  if (valid && cnt) atomicAdd(&counts[i], cnt);
}

__global__ void k_max(const int* __restrict__ counts, const float* __restrict__ min_d,
                      int* __restrict__ maxn, int N) {
  int i = blockIdx.x * blockDim.x + threadIdx.x;
  int c = 0;
  if (i < N && min_d[i] > 8.0f) c = counts[i];
  for (int off = 32; off > 0; off >>= 1) {
    int o = __shfl_down(c, off, 64);
    c = c > o ? c : o;
  }
  if ((threadIdx.x & 63) == 0) atomicMax(maxn, c);
}

// Tiered score * bonus; build strictly-ordered sort key (score desc, idx asc).
__global__ void k_score(const float* __restrict__ min_d, const int* __restrict__ counts,
                        const int* __restrict__ maxn, const float* __restrict__ x,
                        float* __restrict__ out_scores, uint64_t* __restrict__ keys,
                        int N, int F) {
#pragma clang fp contract(off)
  int i = blockIdx.x * blockDim.x + threadIdx.x;
  if (i >= N) return;
  float md = min_d[i];
  float mn = (float)(*maxn);
  if (!(mn > 0.0f)) mn = 1.0f;
  float score;
  if (md <= 3.5f) {
    score = 10.0f;
  } else if (md <= 8.0f) {
    score = 5.0f * (8.0f - md) / 8.0f;
  } else {
    float cf = (float)counts[i];
    score = 1.0f - cf / (mn + 1e-6f);
  }
  int rt = (int)x[(size_t)i * F + 1];
  rt = rt < 0 ? 0 : (rt > 19 ? 19 : rt);
  score = score * BOND[rt];
  out_scores[i] = score;
  uint32_t fb = __float_as_uint(score);  // score >= 0 -> bits monotone
  keys[i] = ((uint64_t)fb << 32) | (uint64_t)(0x7FFFFFFFu - (uint32_t)i);
}

// rank[i] = #{ j : key_j > key_i }  (keys strictly ordered -> permutation)
__global__ void k_rank(const uint64_t* __restrict__ keys, int* __restrict__ rankv,
                       int N, int jChunk) {
  __shared__ uint64_t sk[TILE];
  int t = threadIdx.x;
  int i = blockIdx.x * TILE + t;
  bool valid = i < N;
  uint64_t ki = valid ? keys[i] : ~0ull;
  int j0 = blockIdx.y * jChunk;
  int j1 = j0 + jChunk;
  if (j1 > N) j1 = N;
  int r = 0;
  for (int jb = j0; jb < j1; jb += TILE) {
    __syncthreads();
    sk[t] = (jb + t < N) ? keys[jb + t] : 0ull;
    __syncthreads();
#pragma unroll 16
    for (int jj = 0; jj < TILE; ++jj) r += (sk[jj] > ki) ? 1 : 0;
  }
  if (valid && r) atomicAdd(&rankv[i], r);
}

__global__ void k_emit(const int* __restrict__ rankv, const float* __restrict__ scores,
                       float* __restrict__ top_scores, float* __restrict__ top_idx,
                       int N, int K) {
  int i = blockIdx.x * blockDim.x + threadIdx.x;
  if (i >= N) return;
  int r = rankv[i];
  if (r < K) {
    top_scores[r] = scores[i];
    top_idx[r] = (float)i;
  }
}

extern "C" void kernel_launch(void* const* d_in, const int* in_sizes, int n_in,
                              void* d_out, int out_size, void* d_ws, size_t ws_size,
                              hipStream_t stream) {
  const float* pos = (const float*)d_in[0];
  const float* lig = (const float*)d_in[1];
  const float* x   = (const float*)d_in[2];
  int N = in_sizes[0] / 3;
  int M = in_sizes[1] / 3;
  int F = in_sizes[2] / N;
  int K = (out_size - N) / 2;

  char* ws = (char*)d_ws;
  float4*   posj   = (float4*)ws;                          // N*16 B
  uint64_t* keys   = (uint64_t*)(ws + (size_t)N * 16);     // N*8 B
  float*    min_d  = (float*)(ws + (size_t)N * 24);        // N*4 B
  int*      counts = (int*)(ws + (size_t)N * 28);          // N*4 B
  int*      rankv  = (int*)(ws + (size_t)N * 32);          // N*4 B
  int*      maxn   = (int*)(ws + (size_t)N * 36);          // 4 B

  float* out_scores = (float*)d_out;
  float* out_top    = out_scores + N;
  float* out_idx    = out_top + K;

  int nb = (N + TILE - 1) / TILE;
  const int JSPLIT = 16;
  int jChunk = (N + JSPLIT - 1) / JSPLIT;
  jChunk = ((jChunk + TILE - 1) / TILE) * TILE;

  hipLaunchKernelGGL(k_init,     dim3(nb), dim3(TILE), 0, stream, counts, rankv, maxn, N);
  hipLaunchKernelGGL(k_classify, dim3(nb), dim3(TILE), 0, stream, pos, lig, min_d, posj, N, M);
  hipLaunchKernelGGL(k_count,    dim3(nb, JSPLIT), dim3(TILE), 0, stream, pos, posj, counts, N, jChunk);
  hipLaunchKernelGGL(k_max,      dim3(nb), dim3(TILE), 0, stream, counts, min_d, maxn, N);
  hipLaunchKernelGGL(k_score,    dim3(nb), dim3(TILE), 0, stream, min_d, counts, maxn, x, out_scores, keys, N, F);
  hipLaunchKernelGGL(k_rank,     dim3(nb, JSPLIT), dim3(TILE), 0, stream, keys, rankv, N, jChunk);
  hipLaunchKernelGGL(k_emit,     dim3(nb), dim3(TILE), 0, stream, rankv, out_scores, out_top, out_idx, N, K);
}